// Round 11
// baseline (1497.992 us; speedup 1.0000x reference)
//
#include <hip/hip_runtime.h>

#define WAVE 64
constexpr int Cc = 128;   // in_channels (fixed by problem: C=128)
constexpr int SH = 2048;  // nodes per shard block (LDS histogram size)

// ---------------- per-node dot products: xw1[u] = x[u]·w[0:C] + b, xw2[u] = x[u]·w[C:2C]
__global__ void k_node_dots(const float* __restrict__ x, const float* __restrict__ w,
                            const float* __restrict__ bptr, float* __restrict__ xw1,
                            float* __restrict__ xw2, int N) {
  int wid = (blockIdx.x * blockDim.x + threadIdx.x) >> 6;
  int lane = threadIdx.x & 63;
  if (wid >= N) return;
  const float2* xr = (const float2*)(x + (size_t)wid * Cc);
  const float2* w2 = (const float2*)w;
  float2 v = xr[lane];
  float2 wa = w2[lane];       // w[2l], w[2l+1]       (first C weights)
  float2 wb = w2[lane + 64];  // w[C+2l], w[C+2l+1]   (second C weights)
  float s1 = v.x * wa.x + v.y * wa.y;
  float s2 = v.x * wb.x + v.y * wb.y;
#pragma unroll
  for (int off = 32; off >= 1; off >>= 1) {
    s1 += __shfl_xor(s1, off);
    s2 += __shfl_xor(s2, off);
  }
  if (lane == 0) {
    xw1[wid] = s1 + bptr[0];
    xw2[wid] = s2;
  }
}

// ---------------- edge scores + contracted-edge compaction (NO global atomics except
// one wave-aggregated counter bump; memory-side atomic write-through made per-edge
// atomics cost ~32B HBM write each -> moved counting to LDS-sharded kernels below)
__global__ void k_edge_score(const int* __restrict__ src, const int* __restrict__ dst,
                             const float* __restrict__ xw1, const float* __restrict__ xw2,
                             float* __restrict__ score, int2* __restrict__ cedge,
                             int* __restrict__ count, int E) {
  int e = blockIdx.x * blockDim.x + threadIdx.x;
  int lane = threadIdx.x & 63;
  int s = 0, d = 0;
  bool con = false;
  if (e < E) {
    s = src[e];
    d = dst[e];
    float arg = xw1[s] + xw2[d];  // xw1 already includes bias
    score[e] = tanhf(arg);
    con = arg > 0.0f;  // tanh(arg) > 0  <=>  arg > 0 (exact, tanh preserves sign)
  }
  unsigned long long m = __ballot(con);
  int cnt = __popcll(m);
  if (cnt == 0) return;
  int leader = __ffsll((unsigned long long)m) - 1;
  int base = 0;
  if (lane == leader) base = atomicAdd(count, cnt);
  base = __shfl(base, leader);
  if (con) {
    int pfx = __popcll(m & ((1ull << lane) - 1ull));
    cedge[base + pfx] = make_int2(s, d);
  }
}

// ---------------- sharded count: per-src edge counts + touched flags + lab iota.
// Each block owns SH nodes, streams src[] and cedge[] with LDS histograms.
__global__ void k_count(const int* __restrict__ src, const int2* __restrict__ cedge,
                        const int* __restrict__ count, int* __restrict__ cnt_src,
                        int* __restrict__ touched, int* __restrict__ lab, int E, int N) {
  __shared__ int cnt[SH];
  __shared__ int tch[SH];
  int lo = blockIdx.x * SH;
  for (int i = threadIdx.x; i < SH; i += blockDim.x) {
    cnt[i] = 0;
    tch[i] = 0;
  }
  __syncthreads();
  for (int e = threadIdx.x; e < E; e += blockDim.x) {
    unsigned r = (unsigned)(src[e] - lo);
    if (r < SH) atomicAdd(&cnt[r], 1);
  }
  int M = *count;
  for (int i = threadIdx.x; i < M; i += blockDim.x) {
    int2 p = cedge[i];
    unsigned rs = (unsigned)(p.x - lo), rd = (unsigned)(p.y - lo);
    if (rs < SH) tch[rs] = 1;  // racy same-value store: fine
    if (rd < SH) tch[rd] = 1;
  }
  __syncthreads();
  for (int i = threadIdx.x; i < SH; i += blockDim.x) {
    int g = lo + i;
    if (g < N) {
      cnt_src[g] = cnt[i];
      touched[g] = tch[i];
      lab[g] = g;  // folded iota
    }
  }
}

// fused relax+jump: one launch per CC iteration. Monotone atomicMin => any interleave
// converges to the same fixed point (min node index per component).
__global__ void k_cc_pass(const int2* __restrict__ ce, const int* __restrict__ count,
                          int* __restrict__ lab, int N) {
  int i = blockIdx.x * blockDim.x + threadIdx.x;
  int M = *count;
  if (i < M) {
    int2 p = ce[i];
    int a = lab[p.x], b = lab[p.y];
    if (a < b) atomicMin(&lab[p.y], a);
    else if (b < a) atomicMin(&lab[p.x], b);
  }
  if (i < N) {
    int a = lab[i];
    int b = lab[a];
    if (b < a) atomicMin(&lab[i], b);
  }
}

// ---------------- CSR offsets: exclusive scan of cnt_src (single block, 1024 threads)
__global__ void k_scan(const int* __restrict__ cnt, int* __restrict__ off_arr, int N) {
  __shared__ int part[1024];
  int t = threadIdx.x;
  int chunk = (N + 1023) / 1024;
  int lo = t * chunk, hi = min(lo + chunk, N);
  int s = 0;
  for (int i = lo; i < hi; ++i) s += cnt[i];
  part[t] = s;
  __syncthreads();
  for (int d = 1; d < 1024; d <<= 1) {
    int v = (t >= d) ? part[t - d] : 0;
    __syncthreads();
    part[t] += v;
    __syncthreads();
  }
  int run = (t == 0) ? 0 : part[t - 1];
  for (int i = lo; i < hi; ++i) {
    off_arr[i] = run;
    run += cnt[i];
  }
}

// ---------------- sharded scatter: LDS cursors (no global atomics)
__global__ void k_scatter(const int* __restrict__ src, const int* __restrict__ dst,
                          const float* __restrict__ score, const int* __restrict__ csr_off,
                          int2* __restrict__ pack, int E, int N) {
  __shared__ int cur[SH];
  int lo = blockIdx.x * SH;
  for (int i = threadIdx.x; i < SH; i += blockDim.x) {
    int g = lo + i;
    cur[i] = (g < N) ? csr_off[g] : 0;
  }
  __syncthreads();
  for (int e = threadIdx.x; e < E; e += blockDim.x) {
    unsigned r = (unsigned)(src[e] - lo);
    if (r < SH) {
      int slot = atomicAdd(&cur[r], 1);  // LDS atomic: on-CU, cheap
      pack[slot] = make_int2(dst[e], __float_as_int(score[e]));
    }
  }
}

// gather: sx[u] = sum_{edges (u,v)} score * x[v]  (+ x[u] if untouched)
// non-atomic full-row float2 store. One wave per node.
__global__ void k_sx_csr(const int2* __restrict__ pack, const int* __restrict__ csr_off,
                         const int* __restrict__ cnt_src, const int* __restrict__ touched,
                         const float* __restrict__ x, float* __restrict__ sx, int N) {
  int wid = (blockIdx.x * blockDim.x + threadIdx.x) >> 6;
  int lane = threadIdx.x & 63;
  if (wid >= N) return;
  int beg = csr_off[wid], num = cnt_src[wid];
  float ax = 0.f, ay = 0.f;
  for (int k = 0; k < num; ++k) {
    int2 p = pack[beg + k];
    float t = __int_as_float(p.y);
    float2 v = ((const float2*)(x + (size_t)p.x * Cc))[lane];
    ax += t * v.x;
    ay += t * v.y;
  }
  if (touched[wid] == 0) {
    float2 v = ((const float2*)(x + (size_t)wid * Cc))[lane];
    ax += v.x;
    ay += v.y;
  }
  ((float2*)(sx + (size_t)wid * Cc))[lane] = make_float2(ax, ay);
}

// x_out[cluster] += sx, run-length compressed. 4 waves/block, 16 nodes/wave,
// y-dim = column half. (singles already folded into sx)
__global__ void k_segsum(const float* __restrict__ sx, const int* __restrict__ lab,
                         float* __restrict__ xout, int N) {
  const int CHUNK = 16;
  int wv = threadIdx.x >> 6;
  int lane = threadIdx.x & 63;
  int j = (blockIdx.y << 6) | lane;
  int u0 = (blockIdx.x * 4 + wv) * CHUNK;
  if (u0 >= N) return;
  int u1 = min(u0 + CHUNK, N);
  int prevc = lab[u0];
  float acc = 0.f;
  for (int u = u0; u < u1; ++u) {
    int c = lab[u];
    float v = sx[(size_t)u * Cc + j];
    if (c != prevc) {
      atomicAdd(&xout[(size_t)prevc * Cc + j], acc);
      acc = 0.f;
      prevc = c;
    }
    acc += v;
  }
  atomicAdd(&xout[(size_t)prevc * Cc + j], acc);
}

__global__ void k_edges_out(const int* __restrict__ src, const int* __restrict__ dst,
                            const int* __restrict__ lab, float* __restrict__ out_ei, int E) {
  int e = blockIdx.x * blockDim.x + threadIdx.x;
  if (e >= E) return;
  out_ei[e] = (float)lab[src[e]];
  out_ei[E + e] = (float)lab[dst[e]];
}

// wave-aggregated: one atomicMax per distinct cluster per wave
__global__ void k_nodes_out(const int* __restrict__ lab, const int* __restrict__ batch,
                            float* __restrict__ out_cluster, float* __restrict__ out_batch,
                            int N) {
  int i = blockIdx.x * blockDim.x + threadIdx.x;
  int lane = threadIdx.x & 63;
  bool valid = i < N;
  int c = valid ? lab[i] : -1;
  float bv = valid ? (float)batch[i] : -1.f;
  if (valid) out_cluster[i] = (float)c;
  unsigned long long remaining = __ballot(valid);
  while (remaining) {
    int leader = __ffsll((unsigned long long)remaining) - 1;
    int lc = __shfl(c, leader);
    bool mine = valid && (c == lc);
    unsigned long long grp = __ballot(mine);
    float v = mine ? bv : -1.f;
#pragma unroll
    for (int off = 32; off >= 1; off >>= 1) v = fmaxf(v, __shfl_xor(v, off));
    if (lane == leader) atomicMax((int*)&out_batch[lc], __float_as_int(v));
    remaining &= ~grp;
  }
}

extern "C" void kernel_launch(void* const* d_in, const int* in_sizes, int n_in,
                              void* d_out, int out_size, void* d_ws, size_t ws_size,
                              hipStream_t stream) {
  const float* x = (const float*)d_in[0];
  const int* ei = (const int*)d_in[1];
  const int* batch = (const int*)d_in[2];
  const float* w = (const float*)d_in[3];
  const float* b = (const float*)d_in[4];
  const int N = in_sizes[2];
  const int E = in_sizes[1] / 2;
  const int* src = ei;
  const int* dst = ei + E;
  const int nshard = (N + SH - 1) / SH;

  char* ws = (char*)d_ws;
  size_t off = 0;
  auto alloc = [&](size_t bytes) -> void* {
    void* p = ws + off;
    off = (off + bytes + 255) & ~(size_t)255;
    return p;
  };
  int* count = (int*)alloc(256);
  const size_t zero_bytes = off;  // only count needs zeroing
  float* sx = (float*)alloc((size_t)N * Cc * 4);
  float* xw1 = (float*)alloc((size_t)N * 4);
  float* xw2 = (float*)alloc((size_t)N * 4);
  float* score = (float*)alloc((size_t)E * 4);
  int* lab = (int*)alloc((size_t)N * 4);
  int* cnt_src = (int*)alloc((size_t)N * 4);
  int* touched = (int*)alloc((size_t)N * 4);
  int* csr_off = (int*)alloc((size_t)N * 4);
  int2* pack = (int2*)alloc((size_t)E * 8);
  int2* cedge = (int2*)alloc((size_t)E * 8);
  (void)ws_size;  // layout (~43MB) fits: round-10 run used a larger layout successfully

  float* out_x = (float*)d_out;
  float* out_ei = out_x + (size_t)N * Cc;
  float* out_batch = out_ei + 2 * (size_t)E;
  float* out_cluster = out_batch + N;

  hipMemsetAsync(d_out, 0, (size_t)out_size * 4, stream);
  hipMemsetAsync(d_ws, 0, zero_bytes, stream);

  k_node_dots<<<(N + 3) / 4, 256, 0, stream>>>(x, w, b, xw1, xw2, N);
  k_edge_score<<<(E + 255) / 256, 256, 0, stream>>>(src, dst, xw1, xw2, score, cedge, count, E);
  k_count<<<nshard, 1024, 0, stream>>>(src, cedge, count, cnt_src, touched, lab, E, N);
  for (int it = 0; it < 12; ++it) {
    k_cc_pass<<<(E + 255) / 256, 256, 0, stream>>>(cedge, count, lab, N);
  }
  k_scan<<<1, 1024, 0, stream>>>(cnt_src, csr_off, N);
  k_scatter<<<nshard, 1024, 0, stream>>>(src, dst, score, csr_off, pack, E, N);
  k_sx_csr<<<(N + 3) / 4, 256, 0, stream>>>(pack, csr_off, cnt_src, touched, x, sx, N);
  k_segsum<<<dim3((N + 63) / 64, 2), 256, 0, stream>>>(sx, lab, out_x, N);
  k_edges_out<<<(E + 255) / 256, 256, 0, stream>>>(src, dst, lab, out_ei, E);
  k_nodes_out<<<(N + 255) / 256, 256, 0, stream>>>(lab, batch, out_cluster, out_batch, N);
}

// Round 12
// 667.987 us; speedup vs baseline: 2.2425x; 2.2425x over previous
//
#include <hip/hip_runtime.h>

constexpr int Cc = 128;   // in_channels (fixed: C=128)
constexpr int NB = 1024;  // bucket table width; bucket = src>>6, needs N <= 65536 (N=50000)
constexpr int CH = 256;   // edge-chunk blocks for hist/scatter passes

// ---------------- per-node dot products: xw1[u] = x[u]·w[0:C] + b, xw2[u] = x[u]·w[C:2C]
__global__ void k_node_dots(const float* __restrict__ x, const float* __restrict__ w,
                            const float* __restrict__ bptr, float* __restrict__ xw1,
                            float* __restrict__ xw2, int N) {
  int wid = (blockIdx.x * blockDim.x + threadIdx.x) >> 6;
  int lane = threadIdx.x & 63;
  if (wid >= N) return;
  const float2* xr = (const float2*)(x + (size_t)wid * Cc);
  const float2* w2 = (const float2*)w;
  float2 v = xr[lane];
  float2 wa = w2[lane];
  float2 wb = w2[lane + 64];
  float s1 = v.x * wa.x + v.y * wa.y;
  float s2 = v.x * wb.x + v.y * wb.y;
#pragma unroll
  for (int off = 32; off >= 1; off >>= 1) {
    s1 += __shfl_xor(s1, off);
    s2 += __shfl_xor(s2, off);
  }
  if (lane == 0) {
    xw1[wid] = s1 + bptr[0];
    xw2[wid] = s2;
  }
}

// ---------------- edge scores + contracted-edge compaction + touched flags.
// NO per-edge global RMW atomics (they write through to HBM ~32B each; r10 evidence).
__global__ void k_edge_score(const int* __restrict__ src, const int* __restrict__ dst,
                             const float* __restrict__ xw1, const float* __restrict__ xw2,
                             float* __restrict__ score, int2* __restrict__ cedge,
                             int* __restrict__ count, int* __restrict__ touched, int E) {
  int e = blockIdx.x * blockDim.x + threadIdx.x;
  int lane = threadIdx.x & 63;
  int s = 0, d = 0;
  bool con = false;
  if (e < E) {
    s = src[e];
    d = dst[e];
    float arg = xw1[s] + xw2[d];  // xw1 already includes bias
    score[e] = tanhf(arg);
    con = arg > 0.0f;  // tanh(arg) > 0 <=> arg > 0 (exact)
    if (con) {
      touched[s] = 1;  // racy same-value stores: benign
      touched[d] = 1;
    }
  }
  unsigned long long m = __ballot(con);
  int cnt = __popcll(m);
  if (cnt == 0) return;
  int leader = __ffsll((unsigned long long)m) - 1;
  int base = 0;
  if (lane == leader) base = atomicAdd(count, cnt);
  base = __shfl(base, leader);
  if (con) {
    int pfx = __popcll(m & ((1ull << lane) - 1ull));
    cedge[base + pfx] = make_int2(s, d);
  }
}

__global__ void k_iota(int* __restrict__ lab, int N) {
  int i = blockIdx.x * blockDim.x + threadIdx.x;
  if (i < N) lab[i] = i;
}

// fused relax+jump; monotone atomicMin -> schedule-independent fixed point
__global__ void k_cc_pass(const int2* __restrict__ ce, const int* __restrict__ count,
                          int* __restrict__ lab, int N) {
  int i = blockIdx.x * blockDim.x + threadIdx.x;
  int M = *count;
  if (i < M) {
    int2 p = ce[i];
    int a = lab[p.x], b = lab[p.y];
    if (a < b) atomicMin(&lab[p.y], a);
    else if (b < a) atomicMin(&lab[p.x], b);
  }
  if (i < N) {
    int a = lab[i];
    int b = lab[a];
    if (b < a) atomicMin(&lab[i], b);
  }
}

// ---------------- counting sort pass 1: per-chunk bucket histograms (LDS only)
__global__ void k_hist(const int* __restrict__ src, int* __restrict__ T, int E) {
  __shared__ int h[NB];
  for (int i = threadIdx.x; i < NB; i += blockDim.x) h[i] = 0;
  __syncthreads();
  int ch = (E + gridDim.x - 1) / gridDim.x;
  int lo = blockIdx.x * ch, hi = min(lo + ch, E);
  for (int e = lo + threadIdx.x; e < hi; e += blockDim.x) atomicAdd(&h[src[e] >> 6], 1);
  __syncthreads();
  for (int i = threadIdx.x; i < NB; i += blockDim.x) T[blockIdx.x * NB + i] = h[i];
}

// ---------------- pass 2: scan -> per-(chunk,bucket) global bases + bucket ranges bb[]
__global__ void k_scanT(int* __restrict__ T, int* __restrict__ bb, int C, int nb) {
  __shared__ int part[1024];
  int b = threadIdx.x;
  int tot = 0;
  for (int c = 0; c < C; ++c) tot += T[c * NB + b];
  part[b] = tot;
  __syncthreads();
  for (int d = 1; d < 1024; d <<= 1) {
    int v = (b >= d) ? part[b - d] : 0;
    __syncthreads();
    part[b] += v;
    __syncthreads();
  }
  int base = (b == 0) ? 0 : part[b - 1];  // exclusive prefix over buckets
  if (b <= nb) bb[b] = base;              // bb[nb] == E (buckets >= nb are empty)
  int run = base;
  for (int c = 0; c < C; ++c) {
    int v = T[c * NB + b];
    T[c * NB + b] = run;
    run += v;
  }
}

// ---------------- pass 3: scatter edge ids grouped by bucket (LDS cursors, deterministic)
__global__ void k_scat2(const int* __restrict__ src, const int* __restrict__ T,
                        int* __restrict__ pk, int E) {
  __shared__ int cur[NB];
  for (int i = threadIdx.x; i < NB; i += blockDim.x) cur[i] = T[blockIdx.x * NB + i];
  __syncthreads();
  int ch = (E + gridDim.x - 1) / gridDim.x;
  int lo = blockIdx.x * ch, hi = min(lo + ch, E);
  for (int e = lo + threadIdx.x; e < hi; e += blockDim.x) {
    int slot = atomicAdd(&cur[src[e] >> 6], 1);  // LDS atomic
    pk[slot] = e;
  }
}

// ---------------- pass 4: within-bucket sort by node -> pack(dst,score), cnt_src, csr_off
__global__ void k_bucket(const int* __restrict__ pk, const int* __restrict__ bb,
                         const int* __restrict__ src, const int* __restrict__ dst,
                         const float* __restrict__ score, int* __restrict__ cnt_src,
                         int* __restrict__ csr_off, int2* __restrict__ pack, int N) {
  int b = blockIdx.x;
  int lo = bb[b], hi = bb[b + 1];
  __shared__ int h[64], off_s[64], cur[64];
  if (threadIdx.x < 64) h[threadIdx.x] = 0;
  __syncthreads();
  for (int i = lo + threadIdx.x; i < hi; i += blockDim.x) atomicAdd(&h[src[pk[i]] & 63], 1);
  __syncthreads();
  if (threadIdx.x == 0) {
    int run = lo;
    for (int j = 0; j < 64; ++j) {
      off_s[j] = run;
      run += h[j];
    }
  }
  __syncthreads();
  if (threadIdx.x < 64) {
    cur[threadIdx.x] = off_s[threadIdx.x];
    int g = (b << 6) + threadIdx.x;
    if (g < N) {
      csr_off[g] = off_s[threadIdx.x];
      cnt_src[g] = h[threadIdx.x];
    }
  }
  __syncthreads();
  for (int i = lo + threadIdx.x; i < hi; i += blockDim.x) {
    int e = pk[i];
    int slot = atomicAdd(&cur[src[e] & 63], 1);  // LDS atomic
    pack[slot] = make_int2(dst[e], __float_as_int(score[e]));
  }
}

// gather: sx[u] = sum_edges score * x[dst] (+ x[u] if untouched); non-atomic row store
__global__ void k_sx_csr(const int2* __restrict__ pack, const int* __restrict__ csr_off,
                         const int* __restrict__ cnt_src, const int* __restrict__ touched,
                         const float* __restrict__ x, float* __restrict__ sx, int N) {
  int wid = (blockIdx.x * blockDim.x + threadIdx.x) >> 6;
  int lane = threadIdx.x & 63;
  if (wid >= N) return;
  int beg = csr_off[wid], num = cnt_src[wid];
  float ax = 0.f, ay = 0.f;
  for (int k = 0; k < num; ++k) {
    int2 p = pack[beg + k];
    float t = __int_as_float(p.y);
    float2 v = ((const float2*)(x + (size_t)p.x * Cc))[lane];
    ax += t * v.x;
    ay += t * v.y;
  }
  if (touched[wid] == 0) {
    float2 v = ((const float2*)(x + (size_t)wid * Cc))[lane];
    ax += v.x;
    ay += v.y;
  }
  ((float2*)(sx + (size_t)wid * Cc))[lane] = make_float2(ax, ay);
}

// x_out[cluster] += sx, run-length compressed (singles already folded into sx)
__global__ void k_segsum(const float* __restrict__ sx, const int* __restrict__ lab,
                         float* __restrict__ xout, int N) {
  const int CHUNK = 16;
  int wv = threadIdx.x >> 6;
  int lane = threadIdx.x & 63;
  int j = (blockIdx.y << 6) | lane;
  int u0 = (blockIdx.x * 4 + wv) * CHUNK;
  if (u0 >= N) return;
  int u1 = min(u0 + CHUNK, N);
  int prevc = lab[u0];
  float acc = 0.f;
  for (int u = u0; u < u1; ++u) {
    int c = lab[u];
    float v = sx[(size_t)u * Cc + j];
    if (c != prevc) {
      atomicAdd(&xout[(size_t)prevc * Cc + j], acc);
      acc = 0.f;
      prevc = c;
    }
    acc += v;
  }
  atomicAdd(&xout[(size_t)prevc * Cc + j], acc);
}

__global__ void k_edges_out(const int* __restrict__ src, const int* __restrict__ dst,
                            const int* __restrict__ lab, float* __restrict__ out_ei, int E) {
  int e = blockIdx.x * blockDim.x + threadIdx.x;
  if (e >= E) return;
  out_ei[e] = (float)lab[src[e]];
  out_ei[E + e] = (float)lab[dst[e]];
}

// wave-aggregated: one atomicMax per distinct cluster per wave
__global__ void k_nodes_out(const int* __restrict__ lab, const int* __restrict__ batch,
                            float* __restrict__ out_cluster, float* __restrict__ out_batch,
                            int N) {
  int i = blockIdx.x * blockDim.x + threadIdx.x;
  int lane = threadIdx.x & 63;
  bool valid = i < N;
  int c = valid ? lab[i] : -1;
  float bv = valid ? (float)batch[i] : -1.f;
  if (valid) out_cluster[i] = (float)c;
  unsigned long long remaining = __ballot(valid);
  while (remaining) {
    int leader = __ffsll((unsigned long long)remaining) - 1;
    int lc = __shfl(c, leader);
    bool mine = valid && (c == lc);
    unsigned long long grp = __ballot(mine);
    float v = mine ? bv : -1.f;
#pragma unroll
    for (int off = 32; off >= 1; off >>= 1) v = fmaxf(v, __shfl_xor(v, off));
    if (lane == leader) atomicMax((int*)&out_batch[lc], __float_as_int(v));
    remaining &= ~grp;
  }
}

extern "C" void kernel_launch(void* const* d_in, const int* in_sizes, int n_in,
                              void* d_out, int out_size, void* d_ws, size_t ws_size,
                              hipStream_t stream) {
  const float* x = (const float*)d_in[0];
  const int* ei = (const int*)d_in[1];
  const int* batch = (const int*)d_in[2];
  const float* w = (const float*)d_in[3];
  const float* b = (const float*)d_in[4];
  const int N = in_sizes[2];
  const int E = in_sizes[1] / 2;
  const int* src = ei;
  const int* dst = ei + E;
  const int nb = (N + 63) >> 6;  // buckets; N=50000 -> 782 (<= NB)

  char* ws = (char*)d_ws;
  size_t off = 0;
  auto alloc = [&](size_t bytes) -> void* {
    void* p = ws + off;
    off = (off + bytes + 255) & ~(size_t)255;
    return p;
  };
  int* count = (int*)alloc(256);
  int* touched = (int*)alloc((size_t)N * 4);
  const size_t zero_bytes = off;  // count + touched
  float* xw1 = (float*)alloc((size_t)N * 4);
  float* xw2 = (float*)alloc((size_t)N * 4);
  float* score = (float*)alloc((size_t)E * 4);
  int* lab = (int*)alloc((size_t)N * 4);
  int* cnt_src = (int*)alloc((size_t)N * 4);
  int* csr_off = (int*)alloc((size_t)N * 4);
  int* T = (int*)alloc((size_t)CH * NB * 4);
  int* bb = (int*)alloc((size_t)(NB + 1) * 4);
  int* pk = (int*)alloc((size_t)E * 4);
  int2* pack = (int2*)alloc((size_t)E * 8);
  // sx aliases cedge+pk scratch lifetimes? cedge lives under sx region (disjoint in time):
  float* sx = (float*)alloc((size_t)N * Cc * 4);
  int2* cedge = (int2*)sx;  // first E*8 bytes of sx region; dead before k_sx_csr writes sx
  (void)ws_size;            // total ~41 MB; round-10 run proved >= 43 MB available

  float* out_x = (float*)d_out;
  float* out_ei = out_x + (size_t)N * Cc;
  float* out_batch = out_ei + 2 * (size_t)E;
  float* out_cluster = out_batch + N;

  hipMemsetAsync(d_out, 0, (size_t)out_size * 4, stream);
  hipMemsetAsync(d_ws, 0, zero_bytes, stream);

  k_node_dots<<<(N + 3) / 4, 256, 0, stream>>>(x, w, b, xw1, xw2, N);
  k_edge_score<<<(E + 255) / 256, 256, 0, stream>>>(src, dst, xw1, xw2, score, cedge, count,
                                                    touched, E);
  k_iota<<<(N + 255) / 256, 256, 0, stream>>>(lab, N);
  for (int it = 0; it < 10; ++it) {
    k_cc_pass<<<(E + 255) / 256, 256, 0, stream>>>(cedge, count, lab, N);
  }
  // CSR build (no global atomics): hist -> scan -> bucket-scatter -> node-sort
  k_hist<<<CH, 256, 0, stream>>>(src, T, E);
  k_scanT<<<1, 1024, 0, stream>>>(T, bb, CH, nb);
  k_scat2<<<CH, 256, 0, stream>>>(src, T, pk, E);
  k_bucket<<<nb, 256, 0, stream>>>(pk, bb, src, dst, score, cnt_src, csr_off, pack, N);
  // cedge (aliased under sx) is dead from here on; sx writes may stomp it
  k_sx_csr<<<(N + 3) / 4, 256, 0, stream>>>(pack, csr_off, cnt_src, touched, x, sx, N);
  k_segsum<<<dim3((N + 63) / 64, 2), 256, 0, stream>>>(sx, lab, out_x, N);
  k_edges_out<<<(E + 255) / 256, 256, 0, stream>>>(src, dst, lab, out_ei, E);
  k_nodes_out<<<(N + 255) / 256, 256, 0, stream>>>(lab, batch, out_cluster, out_batch, N);
}

// Round 13
// 521.567 us; speedup vs baseline: 2.8721x; 1.2807x over previous
//
#include <hip/hip_runtime.h>

constexpr int Cc = 128;   // in_channels (fixed: C=128)
constexpr int NB = 1024;  // bucket table width; bucket = src>>6, needs N <= 65536 (N=50000)
constexpr int CH = 64;    // edge-chunk blocks for hist/scatter passes
constexpr int MAXIT = 10; // CC passes

// ---------------- per-node dot products: xw1[u] = x[u]·w[0:C] + b, xw2[u] = x[u]·w[C:2C]
__global__ void k_node_dots(const float* __restrict__ x, const float* __restrict__ w,
                            const float* __restrict__ bptr, float* __restrict__ xw1,
                            float* __restrict__ xw2, int N) {
  int wid = (blockIdx.x * blockDim.x + threadIdx.x) >> 6;
  int lane = threadIdx.x & 63;
  if (wid >= N) return;
  const float2* xr = (const float2*)(x + (size_t)wid * Cc);
  const float2* w2 = (const float2*)w;
  float2 v = xr[lane];
  float2 wa = w2[lane];
  float2 wb = w2[lane + 64];
  float s1 = v.x * wa.x + v.y * wa.y;
  float s2 = v.x * wb.x + v.y * wb.y;
#pragma unroll
  for (int off = 32; off >= 1; off >>= 1) {
    s1 += __shfl_xor(s1, off);
    s2 += __shfl_xor(s2, off);
  }
  if (lane == 0) {
    xw1[wid] = s1 + bptr[0];
    xw2[wid] = s2;
  }
}

// ---------------- edge scores + compaction (block-aggregated counter: 1 global atomic
// per 256-thr block, not per wave — hot-address atomics serialize at ~11ns each, r12)
__global__ void k_edge_score(const int* __restrict__ src, const int* __restrict__ dst,
                             const float* __restrict__ xw1, const float* __restrict__ xw2,
                             float* __restrict__ score, int2* __restrict__ cedge,
                             int* __restrict__ count, int* __restrict__ touched, int E) {
  __shared__ int wcnt[4];
  __shared__ int blockbase;
  int e = blockIdx.x * blockDim.x + threadIdx.x;
  int wv = threadIdx.x >> 6, lane = threadIdx.x & 63;
  int s = 0, d = 0;
  bool con = false;
  if (e < E) {
    s = src[e];
    d = dst[e];
    float arg = xw1[s] + xw2[d];  // xw1 already includes bias
    score[e] = tanhf(arg);
    con = arg > 0.0f;  // tanh(arg) > 0 <=> arg > 0 (exact)
    if (con) {
      touched[s] = 1;  // racy same-value stores: benign
      touched[d] = 1;
    }
  }
  unsigned long long m = __ballot(con);
  int cnt = __popcll(m);
  if (lane == 0) wcnt[wv] = cnt;
  __syncthreads();
  if (threadIdx.x == 0) {
    int t0 = wcnt[0], t1 = wcnt[1], t2 = wcnt[2], t3 = wcnt[3];
    int tot = t0 + t1 + t2 + t3;
    blockbase = tot ? atomicAdd(count, tot) : 0;
    wcnt[0] = 0;
    wcnt[1] = t0;
    wcnt[2] = t0 + t1;
    wcnt[3] = t0 + t1 + t2;
  }
  __syncthreads();
  if (con) {
    int pfx = __popcll(m & ((1ull << lane) - 1ull));
    cedge[blockbase + wcnt[wv] + pfx] = make_int2(s, d);
  }
}

__global__ void k_iota(int* __restrict__ lab, int N) {
  int i = blockIdx.x * blockDim.x + threadIdx.x;
  if (i < N) lab[i] = i;
}

// fused relax+jump with change-flag early exit. Monotone atomicMin -> schedule-
// independent fixed point; a pass with zero changes implies all later passes no-op.
__global__ void k_cc_pass(const int2* __restrict__ ce, const int* __restrict__ count,
                          int* __restrict__ lab, int* __restrict__ flags, int it, int N) {
  if (it > 0 && flags[it - 1] == 0) return;  // previous pass was a full no-op
  int i = blockIdx.x * blockDim.x + threadIdx.x;
  int M = *count;
  bool ch = false;
  if (i < M) {
    int2 p = ce[i];
    int a = lab[p.x], b = lab[p.y];
    if (a < b) {
      if (atomicMin(&lab[p.y], a) > a) ch = true;  // old > a => we lowered it
    } else if (b < a) {
      if (atomicMin(&lab[p.x], b) > b) ch = true;
    }
  }
  if (i < N) {
    int a = lab[i];
    int b = lab[a];
    if (b < a) {
      atomicMin(&lab[i], b);  // guaranteed to lower lab[i] (monotone)
      ch = true;
    }
  }
  if (ch) flags[it] = 1;  // racy same-value store: benign
}

// ---------------- counting sort pass 1: per-chunk bucket histograms (LDS only)
__global__ void k_hist(const int* __restrict__ src, int* __restrict__ T, int E) {
  __shared__ int h[NB];
  for (int i = threadIdx.x; i < NB; i += blockDim.x) h[i] = 0;
  __syncthreads();
  int ch = (E + gridDim.x - 1) / gridDim.x;
  int lo = blockIdx.x * ch, hi = min(lo + ch, E);
  for (int e = lo + threadIdx.x; e < hi; e += blockDim.x) atomicAdd(&h[src[e] >> 6], 1);
  __syncthreads();
  for (int i = threadIdx.x; i < NB; i += blockDim.x) T[blockIdx.x * NB + i] = h[i];
}

// ---------------- pass 2: scan -> per-(chunk,bucket) global bases + bucket ranges bb[]
__global__ void k_scanT(int* __restrict__ T, int* __restrict__ bb, int C, int nb) {
  __shared__ int part[1024];
  int b = threadIdx.x;
  int tot = 0;
  for (int c = 0; c < C; ++c) tot += T[c * NB + b];
  part[b] = tot;
  __syncthreads();
  for (int d = 1; d < 1024; d <<= 1) {
    int v = (b >= d) ? part[b - d] : 0;
    __syncthreads();
    part[b] += v;
    __syncthreads();
  }
  int base = (b == 0) ? 0 : part[b - 1];  // exclusive prefix over buckets
  if (b <= nb) bb[b] = base;              // bb[nb] == E (buckets >= nb are empty)
  int run = base;
  for (int c = 0; c < C; ++c) {
    int v = T[c * NB + b];
    T[c * NB + b] = run;
    run += v;
  }
}

// ---------------- pass 3: scatter edge ids grouped by bucket (LDS cursors, deterministic)
__global__ void k_scat2(const int* __restrict__ src, const int* __restrict__ T,
                        int* __restrict__ pk, int E) {
  __shared__ int cur[NB];
  for (int i = threadIdx.x; i < NB; i += blockDim.x) cur[i] = T[blockIdx.x * NB + i];
  __syncthreads();
  int ch = (E + gridDim.x - 1) / gridDim.x;
  int lo = blockIdx.x * ch, hi = min(lo + ch, E);
  for (int e = lo + threadIdx.x; e < hi; e += blockDim.x) {
    int slot = atomicAdd(&cur[src[e] >> 6], 1);  // LDS atomic
    pk[slot] = e;
  }
}

// ---------------- pass 4: within-bucket sort by node -> pack(dst,score), cnt_src, csr_off
__global__ void k_bucket(const int* __restrict__ pk, const int* __restrict__ bb,
                         const int* __restrict__ src, const int* __restrict__ dst,
                         const float* __restrict__ score, int* __restrict__ cnt_src,
                         int* __restrict__ csr_off, int2* __restrict__ pack, int N) {
  int b = blockIdx.x;
  int lo = bb[b], hi = bb[b + 1];
  __shared__ int h[64], off_s[64], cur[64];
  if (threadIdx.x < 64) h[threadIdx.x] = 0;
  __syncthreads();
  for (int i = lo + threadIdx.x; i < hi; i += blockDim.x) atomicAdd(&h[src[pk[i]] & 63], 1);
  __syncthreads();
  if (threadIdx.x == 0) {
    int run = lo;
    for (int j = 0; j < 64; ++j) {
      off_s[j] = run;
      run += h[j];
    }
  }
  __syncthreads();
  if (threadIdx.x < 64) {
    cur[threadIdx.x] = off_s[threadIdx.x];
    int g = (b << 6) + threadIdx.x;
    if (g < N) {
      csr_off[g] = off_s[threadIdx.x];
      cnt_src[g] = h[threadIdx.x];
    }
  }
  __syncthreads();
  for (int i = lo + threadIdx.x; i < hi; i += blockDim.x) {
    int e = pk[i];
    int slot = atomicAdd(&cur[src[e] & 63], 1);  // LDS atomic
    pack[slot] = make_int2(dst[e], __float_as_int(score[e]));
  }
}

// gather: sx[u] = sum_edges score * x[dst] (+ x[u] if untouched); non-atomic row store
__global__ void k_sx_csr(const int2* __restrict__ pack, const int* __restrict__ csr_off,
                         const int* __restrict__ cnt_src, const int* __restrict__ touched,
                         const float* __restrict__ x, float* __restrict__ sx, int N) {
  int wid = (blockIdx.x * blockDim.x + threadIdx.x) >> 6;
  int lane = threadIdx.x & 63;
  if (wid >= N) return;
  int beg = csr_off[wid], num = cnt_src[wid];
  float ax = 0.f, ay = 0.f;
  for (int k = 0; k < num; ++k) {
    int2 p = pack[beg + k];
    float t = __int_as_float(p.y);
    float2 v = ((const float2*)(x + (size_t)p.x * Cc))[lane];
    ax += t * v.x;
    ay += t * v.y;
  }
  if (touched[wid] == 0) {
    float2 v = ((const float2*)(x + (size_t)wid * Cc))[lane];
    ax += v.x;
    ay += v.y;
  }
  ((float2*)(sx + (size_t)wid * Cc))[lane] = make_float2(ax, ay);
}

// x_out[cluster] += sx, run-length compressed (singles already folded into sx)
__global__ void k_segsum(const float* __restrict__ sx, const int* __restrict__ lab,
                         float* __restrict__ xout, int N) {
  const int CHUNK = 16;
  int wv = threadIdx.x >> 6;
  int lane = threadIdx.x & 63;
  int j = (blockIdx.y << 6) | lane;
  int u0 = (blockIdx.x * 4 + wv) * CHUNK;
  if (u0 >= N) return;
  int u1 = min(u0 + CHUNK, N);
  int prevc = lab[u0];
  float acc = 0.f;
  for (int u = u0; u < u1; ++u) {
    int c = lab[u];
    float v = sx[(size_t)u * Cc + j];
    if (c != prevc) {
      atomicAdd(&xout[(size_t)prevc * Cc + j], acc);
      acc = 0.f;
      prevc = c;
    }
    acc += v;
  }
  atomicAdd(&xout[(size_t)prevc * Cc + j], acc);
}

__global__ void k_edges_out(const int* __restrict__ src, const int* __restrict__ dst,
                            const int* __restrict__ lab, float* __restrict__ out_ei, int E) {
  int e = blockIdx.x * blockDim.x + threadIdx.x;
  if (e >= E) return;
  out_ei[e] = (float)lab[src[e]];
  out_ei[E + e] = (float)lab[dst[e]];
}

// wave-aggregated: one atomicMax per distinct cluster per wave
__global__ void k_nodes_out(const int* __restrict__ lab, const int* __restrict__ batch,
                            float* __restrict__ out_cluster, float* __restrict__ out_batch,
                            int N) {
  int i = blockIdx.x * blockDim.x + threadIdx.x;
  int lane = threadIdx.x & 63;
  bool valid = i < N;
  int c = valid ? lab[i] : -1;
  float bv = valid ? (float)batch[i] : -1.f;
  if (valid) out_cluster[i] = (float)c;
  unsigned long long remaining = __ballot(valid);
  while (remaining) {
    int leader = __ffsll((unsigned long long)remaining) - 1;
    int lc = __shfl(c, leader);
    bool mine = valid && (c == lc);
    unsigned long long grp = __ballot(mine);
    float v = mine ? bv : -1.f;
#pragma unroll
    for (int off = 32; off >= 1; off >>= 1) v = fmaxf(v, __shfl_xor(v, off));
    if (lane == leader) atomicMax((int*)&out_batch[lc], __float_as_int(v));
    remaining &= ~grp;
  }
}

extern "C" void kernel_launch(void* const* d_in, const int* in_sizes, int n_in,
                              void* d_out, int out_size, void* d_ws, size_t ws_size,
                              hipStream_t stream) {
  const float* x = (const float*)d_in[0];
  const int* ei = (const int*)d_in[1];
  const int* batch = (const int*)d_in[2];
  const float* w = (const float*)d_in[3];
  const float* b = (const float*)d_in[4];
  const int N = in_sizes[2];
  const int E = in_sizes[1] / 2;
  const int* src = ei;
  const int* dst = ei + E;
  const int nb = (N + 63) >> 6;  // buckets; N=50000 -> 782 (<= NB)

  char* ws = (char*)d_ws;
  size_t off = 0;
  auto alloc = [&](size_t bytes) -> void* {
    void* p = ws + off;
    off = (off + bytes + 255) & ~(size_t)255;
    return p;
  };
  int* count = (int*)alloc(256);
  int* flags = (int*)alloc((size_t)MAXIT * 4);
  int* touched = (int*)alloc((size_t)N * 4);
  const size_t zero_bytes = off;  // count + flags + touched
  float* xw1 = (float*)alloc((size_t)N * 4);
  float* xw2 = (float*)alloc((size_t)N * 4);
  float* score = (float*)alloc((size_t)E * 4);
  int* lab = (int*)alloc((size_t)N * 4);
  int* cnt_src = (int*)alloc((size_t)N * 4);
  int* csr_off = (int*)alloc((size_t)N * 4);
  int* T = (int*)alloc((size_t)CH * NB * 4);
  int* bb = (int*)alloc((size_t)(NB + 1) * 4);
  int* pk = (int*)alloc((size_t)E * 4);
  int2* pack = (int2*)alloc((size_t)E * 8);
  float* sx = (float*)alloc((size_t)N * Cc * 4);
  int2* cedge = (int2*)sx;  // aliased: cedge dead before k_sx_csr writes sx
  (void)ws_size;            // ~41 MB total; r10 proved >= 43 MB available

  float* out_x = (float*)d_out;
  float* out_ei = out_x + (size_t)N * Cc;
  float* out_batch = out_ei + 2 * (size_t)E;
  float* out_cluster = out_batch + N;

  hipMemsetAsync(d_out, 0, (size_t)out_size * 4, stream);
  hipMemsetAsync(d_ws, 0, zero_bytes, stream);

  k_node_dots<<<(N + 3) / 4, 256, 0, stream>>>(x, w, b, xw1, xw2, N);
  k_edge_score<<<(E + 255) / 256, 256, 0, stream>>>(src, dst, xw1, xw2, score, cedge, count,
                                                    touched, E);
  k_iota<<<(N + 255) / 256, 256, 0, stream>>>(lab, N);
  for (int it = 0; it < MAXIT; ++it) {
    k_cc_pass<<<(E + 255) / 256, 256, 0, stream>>>(cedge, count, lab, flags, it, N);
  }
  // CSR build (no global atomics): hist -> scan -> bucket-scatter -> node-sort
  k_hist<<<CH, 256, 0, stream>>>(src, T, E);
  k_scanT<<<1, 1024, 0, stream>>>(T, bb, CH, nb);
  k_scat2<<<CH, 256, 0, stream>>>(src, T, pk, E);
  k_bucket<<<nb, 256, 0, stream>>>(pk, bb, src, dst, score, cnt_src, csr_off, pack, N);
  // cedge (aliased under sx) is dead from here on
  k_sx_csr<<<(N + 3) / 4, 256, 0, stream>>>(pack, csr_off, cnt_src, touched, x, sx, N);
  k_segsum<<<dim3((N + 63) / 64, 2), 256, 0, stream>>>(sx, lab, out_x, N);
  k_edges_out<<<(E + 255) / 256, 256, 0, stream>>>(src, dst, lab, out_ei, E);
  k_nodes_out<<<(N + 255) / 256, 256, 0, stream>>>(lab, batch, out_cluster, out_batch, N);
}

// Round 15
// 482.365 us; speedup vs baseline: 3.1055x; 1.0813x over previous
//
#include <hip/hip_runtime.h>

constexpr int Cc = 128;   // in_channels (fixed: C=128)
constexpr int NB = 1024;  // bucket table width; bucket = src>>6, needs N <= 65536 (N=50000)
constexpr int CH = 64;    // edge-chunk blocks for hist/scatter passes
constexpr int MAXIT = 10; // CC passes

// ---------------- per-node dot products: xw1[u] = x[u]·w[0:C] + b, xw2[u] = x[u]·w[C:2C]
__global__ void k_node_dots(const float* __restrict__ x, const float* __restrict__ w,
                            const float* __restrict__ bptr, float* __restrict__ xw1,
                            float* __restrict__ xw2, int N) {
  int wid = (blockIdx.x * blockDim.x + threadIdx.x) >> 6;
  int lane = threadIdx.x & 63;
  if (wid >= N) return;
  const float2* xr = (const float2*)(x + (size_t)wid * Cc);
  const float2* w2 = (const float2*)w;
  float2 v = xr[lane];
  float2 wa = w2[lane];
  float2 wb = w2[lane + 64];
  float s1 = v.x * wa.x + v.y * wa.y;
  float s2 = v.x * wb.x + v.y * wb.y;
#pragma unroll
  for (int off = 32; off >= 1; off >>= 1) {
    s1 += __shfl_xor(s1, off);
    s2 += __shfl_xor(s2, off);
  }
  if (lane == 0) {
    xw1[wid] = s1 + bptr[0];
    xw2[wid] = s2;
  }
}

// ---------------- edge scores + compaction (block-aggregated counter: 1 global atomic
// per 256-thr block — hot-address atomics serialize at ~11ns each, r12)
__global__ void k_edge_score(const int* __restrict__ src, const int* __restrict__ dst,
                             const float* __restrict__ xw1, const float* __restrict__ xw2,
                             float* __restrict__ score, int2* __restrict__ cedge,
                             int* __restrict__ count, int* __restrict__ touched, int E) {
  __shared__ int wcnt[4];
  __shared__ int blockbase;
  int e = blockIdx.x * blockDim.x + threadIdx.x;
  int wv = threadIdx.x >> 6, lane = threadIdx.x & 63;
  int s = 0, d = 0;
  bool con = false;
  if (e < E) {
    s = src[e];
    d = dst[e];
    float arg = xw1[s] + xw2[d];  // xw1 already includes bias
    score[e] = tanhf(arg);
    con = arg > 0.0f;  // tanh(arg) > 0 <=> arg > 0 (exact)
    if (con) {
      touched[s] = 1;  // racy same-value stores: benign
      touched[d] = 1;
    }
  }
  unsigned long long m = __ballot(con);
  int cnt = __popcll(m);
  if (lane == 0) wcnt[wv] = cnt;
  __syncthreads();
  if (threadIdx.x == 0) {
    int t0 = wcnt[0], t1 = wcnt[1], t2 = wcnt[2], t3 = wcnt[3];
    int tot = t0 + t1 + t2 + t3;
    blockbase = tot ? atomicAdd(count, tot) : 0;
    wcnt[0] = 0;
    wcnt[1] = t0;
    wcnt[2] = t0 + t1;
    wcnt[3] = t0 + t1 + t2;
  }
  __syncthreads();
  if (con) {
    int pfx = __popcll(m & ((1ull << lane) - 1ull));
    cedge[blockbase + wcnt[wv] + pfx] = make_int2(s, d);
  }
}

__global__ void k_iota(int* __restrict__ lab, int N) {
  int i = blockIdx.x * blockDim.x + threadIdx.x;
  if (i < N) lab[i] = i;
}

// fused relax+jump with change-flag early exit. Monotone atomicMin -> schedule-
// independent fixed point; a pass with zero changes implies all later passes no-op.
__global__ void k_cc_pass(const int2* __restrict__ ce, const int* __restrict__ count,
                          int* __restrict__ lab, int* __restrict__ flags, int it, int N) {
  if (it > 0 && flags[it - 1] == 0) return;  // previous pass was a full no-op
  int i = blockIdx.x * blockDim.x + threadIdx.x;
  int M = *count;
  bool ch = false;
  if (i < M) {
    int2 p = ce[i];
    int a = lab[p.x], b = lab[p.y];
    if (a < b) {
      if (atomicMin(&lab[p.y], a) > a) ch = true;
    } else if (b < a) {
      if (atomicMin(&lab[p.x], b) > b) ch = true;
    }
  }
  if (i < N) {
    int a = lab[i];
    int b = lab[a];
    if (b < a) {
      atomicMin(&lab[i], b);
      ch = true;
    }
  }
  if (ch) flags[it] = 1;  // racy same-value store: benign
}

// ---------------- counting sort pass 1: per-chunk bucket histograms (LDS only)
__global__ void k_hist(const int* __restrict__ src, int* __restrict__ T, int E) {
  __shared__ int h[NB];
  for (int i = threadIdx.x; i < NB; i += blockDim.x) h[i] = 0;
  __syncthreads();
  int ch = (E + gridDim.x - 1) / gridDim.x;
  int lo = blockIdx.x * ch, hi = min(lo + ch, E);
  for (int e = lo + threadIdx.x; e < hi; e += blockDim.x) atomicAdd(&h[src[e] >> 6], 1);
  __syncthreads();
  for (int i = threadIdx.x; i < NB; i += blockDim.x) T[blockIdx.x * NB + i] = h[i];
}

// ---------------- pass 2: scan -> per-(chunk,bucket) global bases + bucket ranges bb[]
__global__ void k_scanT(int* __restrict__ T, int* __restrict__ bb, int C, int nb) {
  __shared__ int part[1024];
  int b = threadIdx.x;
  int tot = 0;
  for (int c = 0; c < C; ++c) tot += T[c * NB + b];
  part[b] = tot;
  __syncthreads();
  for (int d = 1; d < 1024; d <<= 1) {
    int v = (b >= d) ? part[b - d] : 0;
    __syncthreads();
    part[b] += v;
    __syncthreads();
  }
  int base = (b == 0) ? 0 : part[b - 1];  // exclusive prefix over buckets
  if (b <= nb) bb[b] = base;              // bb[nb] == E (buckets >= nb are empty)
  int run = base;
  for (int c = 0; c < C; ++c) {
    int v = T[c * NB + b];
    T[c * NB + b] = run;
    run += v;
  }
}

// ---------------- pass 3: scatter edge ids grouped by bucket (LDS cursors, deterministic)
__global__ void k_scat2(const int* __restrict__ src, const int* __restrict__ T,
                        int* __restrict__ pk, int E) {
  __shared__ int cur[NB];
  for (int i = threadIdx.x; i < NB; i += blockDim.x) cur[i] = T[blockIdx.x * NB + i];
  __syncthreads();
  int ch = (E + gridDim.x - 1) / gridDim.x;
  int lo = blockIdx.x * ch, hi = min(lo + ch, E);
  for (int e = lo + threadIdx.x; e < hi; e += blockDim.x) {
    int slot = atomicAdd(&cur[src[e] >> 6], 1);  // LDS atomic
    pk[slot] = e;
  }
}

// ---------------- pass 4: within-bucket sort by node -> pack(dst,score), cnt_src, csr_off
__global__ void k_bucket(const int* __restrict__ pk, const int* __restrict__ bb,
                         const int* __restrict__ src, const int* __restrict__ dst,
                         const float* __restrict__ score, int* __restrict__ cnt_src,
                         int* __restrict__ csr_off, int2* __restrict__ pack, int N) {
  int b = blockIdx.x;
  int lo = bb[b], hi = bb[b + 1];
  __shared__ int h[64], off_s[64], cur[64];
  if (threadIdx.x < 64) h[threadIdx.x] = 0;
  __syncthreads();
  for (int i = lo + threadIdx.x; i < hi; i += blockDim.x) atomicAdd(&h[src[pk[i]] & 63], 1);
  __syncthreads();
  if (threadIdx.x == 0) {
    int run = lo;
    for (int j = 0; j < 64; ++j) {
      off_s[j] = run;
      run += h[j];
    }
  }
  __syncthreads();
  if (threadIdx.x < 64) {
    cur[threadIdx.x] = off_s[threadIdx.x];
    int g = (b << 6) + threadIdx.x;
    if (g < N) {
      csr_off[g] = off_s[threadIdx.x];
      cnt_src[g] = h[threadIdx.x];
    }
  }
  __syncthreads();
  for (int i = lo + threadIdx.x; i < hi; i += blockDim.x) {
    int e = pk[i];
    int slot = atomicAdd(&cur[src[e] & 63], 1);  // LDS atomic
    pack[slot] = make_int2(dst[e], __float_as_int(score[e]));
  }
}

// gather: sx[u] = sum_edges score * x[dst] (+ x[u] if untouched); non-atomic row store
__global__ void k_sx_csr(const int2* __restrict__ pack, const int* __restrict__ csr_off,
                         const int* __restrict__ cnt_src, const int* __restrict__ touched,
                         const float* __restrict__ x, float* __restrict__ sx, int N) {
  int wid = (blockIdx.x * blockDim.x + threadIdx.x) >> 6;
  int lane = threadIdx.x & 63;
  if (wid >= N) return;
  int beg = csr_off[wid], num = cnt_src[wid];
  float ax = 0.f, ay = 0.f;
  for (int k = 0; k < num; ++k) {
    int2 p = pack[beg + k];
    float t = __int_as_float(p.y);
    float2 v = ((const float2*)(x + (size_t)p.x * Cc))[lane];
    ax += t * v.x;
    ay += t * v.y;
  }
  if (touched[wid] == 0) {
    float2 v = ((const float2*)(x + (size_t)wid * Cc))[lane];
    ax += v.x;
    ay += v.y;
  }
  ((float2*)(sx + (size_t)wid * Cc))[lane] = make_float2(ax, ay);
}

// x_out[cluster] += sx, run-length compressed. One wave covers ALL 128 columns via
// float2/lane; CHUNK=128 nodes/wave -> flushes to the giant-component row drop 16x
// (hot-address atomic serialization was the r13 cost; ~11ns/atomic/address).
__global__ void k_segsum(const float* __restrict__ sx, const int* __restrict__ lab,
                         float* __restrict__ xout, int N) {
  const int CHUNK = 128;
  int wv = threadIdx.x >> 6;
  int lane = threadIdx.x & 63;
  int u0 = (blockIdx.x * 4 + wv) * CHUNK;
  if (u0 >= N) return;
  int u1 = min(u0 + CHUNK, N);
  int prevc = lab[u0];
  float ax = 0.f, ay = 0.f;
  for (int u = u0; u < u1; ++u) {
    int c = lab[u];
    float2 v = ((const float2*)(sx + (size_t)u * Cc))[lane];
    if (c != prevc) {
      float* row = xout + (size_t)prevc * Cc + 2 * lane;
      atomicAdd(row, ax);
      atomicAdd(row + 1, ay);
      ax = 0.f;
      ay = 0.f;
      prevc = c;
    }
    ax += v.x;
    ay += v.y;
  }
  float* row = xout + (size_t)prevc * Cc + 2 * lane;
  atomicAdd(row, ax);
  atomicAdd(row + 1, ay);
}

__global__ void k_edges_out(const int* __restrict__ src, const int* __restrict__ dst,
                            const int* __restrict__ lab, float* __restrict__ out_ei, int E) {
  int e = blockIdx.x * blockDim.x + threadIdx.x;
  if (e >= E) return;
  out_ei[e] = (float)lab[src[e]];
  out_ei[E + e] = (float)lab[dst[e]];
}

// wave-aggregated: one atomicMax per distinct cluster per wave
__global__ void k_nodes_out(const int* __restrict__ lab, const int* __restrict__ batch,
                            float* __restrict__ out_cluster, float* __restrict__ out_batch,
                            int N) {
  int i = blockIdx.x * blockDim.x + threadIdx.x;
  int lane = threadIdx.x & 63;
  bool valid = i < N;
  int c = valid ? lab[i] : -1;
  float bv = valid ? (float)batch[i] : -1.f;
  if (valid) out_cluster[i] = (float)c;
  unsigned long long remaining = __ballot(valid);
  while (remaining) {
    int leader = __ffsll((unsigned long long)remaining) - 1;
    int lc = __shfl(c, leader);
    bool mine = valid && (c == lc);
    unsigned long long grp = __ballot(mine);
    float v = mine ? bv : -1.f;
#pragma unroll
    for (int off = 32; off >= 1; off >>= 1) v = fmaxf(v, __shfl_xor(v, off));
    if (lane == leader) atomicMax((int*)&out_batch[lc], __float_as_int(v));
    remaining &= ~grp;
  }
}

extern "C" void kernel_launch(void* const* d_in, const int* in_sizes, int n_in,
                              void* d_out, int out_size, void* d_ws, size_t ws_size,
                              hipStream_t stream) {
  const float* x = (const float*)d_in[0];
  const int* ei = (const int*)d_in[1];
  const int* batch = (const int*)d_in[2];
  const float* w = (const float*)d_in[3];
  const float* b = (const float*)d_in[4];
  const int N = in_sizes[2];
  const int E = in_sizes[1] / 2;
  const int* src = ei;
  const int* dst = ei + E;
  const int nb = (N + 63) >> 6;  // buckets; N=50000 -> 782 (<= NB)

  char* ws = (char*)d_ws;
  size_t off = 0;
  auto alloc = [&](size_t bytes) -> void* {
    void* p = ws + off;
    off = (off + bytes + 255) & ~(size_t)255;
    return p;
  };
  int* count = (int*)alloc(256);
  int* flags = (int*)alloc((size_t)MAXIT * 4);
  int* touched = (int*)alloc((size_t)N * 4);
  const size_t zero_bytes = off;  // count + flags + touched
  float* xw1 = (float*)alloc((size_t)N * 4);
  float* xw2 = (float*)alloc((size_t)N * 4);
  float* score = (float*)alloc((size_t)E * 4);
  int* lab = (int*)alloc((size_t)N * 4);
  int* cnt_src = (int*)alloc((size_t)N * 4);
  int* csr_off = (int*)alloc((size_t)N * 4);
  int* T = (int*)alloc((size_t)CH * NB * 4);
  int* bb = (int*)alloc((size_t)(NB + 1) * 4);
  int* pk = (int*)alloc((size_t)E * 4);
  int2* pack = (int2*)alloc((size_t)E * 8);
  float* sx = (float*)alloc((size_t)N * Cc * 4);
  int2* cedge = (int2*)sx;  // aliased: cedge dead before k_sx_csr writes sx
  (void)ws_size;            // ~41 MB total; r10 proved >= 43 MB available

  float* out_x = (float*)d_out;
  float* out_ei = out_x + (size_t)N * Cc;
  float* out_batch = out_ei + 2 * (size_t)E;
  float* out_cluster = out_batch + N;

  hipMemsetAsync(d_out, 0, (size_t)out_size * 4, stream);
  hipMemsetAsync(d_ws, 0, zero_bytes, stream);

  k_node_dots<<<(N + 3) / 4, 256, 0, stream>>>(x, w, b, xw1, xw2, N);
  k_edge_score<<<(E + 255) / 256, 256, 0, stream>>>(src, dst, xw1, xw2, score, cedge, count,
                                                    touched, E);
  k_iota<<<(N + 255) / 256, 256, 0, stream>>>(lab, N);
  for (int it = 0; it < MAXIT; ++it) {
    k_cc_pass<<<(E + 255) / 256, 256, 0, stream>>>(cedge, count, lab, flags, it, N);
  }
  // CSR build (no global atomics): hist -> scan -> bucket-scatter -> node-sort
  k_hist<<<CH, 256, 0, stream>>>(src, T, E);
  k_scanT<<<1, 1024, 0, stream>>>(T, bb, CH, nb);
  k_scat2<<<CH, 256, 0, stream>>>(src, T, pk, E);
  k_bucket<<<nb, 256, 0, stream>>>(pk, bb, src, dst, score, cnt_src, csr_off, pack, N);
  // cedge (aliased under sx) is dead from here on
  k_sx_csr<<<(N + 3) / 4, 256, 0, stream>>>(pack, csr_off, cnt_src, touched, x, sx, N);
  k_segsum<<<(N + 511) / 512, 256, 0, stream>>>(sx, lab, out_x, N);
  k_edges_out<<<(E + 255) / 256, 256, 0, stream>>>(src, dst, lab, out_ei, E);
  k_nodes_out<<<(N + 255) / 256, 256, 0, stream>>>(lab, batch, out_cluster, out_batch, N);
}

// Round 16
// 424.345 us; speedup vs baseline: 3.5301x; 1.1367x over previous
//
#include <hip/hip_runtime.h>

constexpr int Cc = 128;   // in_channels (fixed: C=128)
constexpr int NB = 1024;  // bucket table width; bucket = src>>6, needs N <= 65536 (N=50000)
constexpr int CH = 64;    // edge-chunk blocks for hist/scatter passes
constexpr int MAXIT = 10; // CC passes

// ---------------- per-node dot products: xw1[u] = x[u]·w[0:C] + b, xw2[u] = x[u]·w[C:2C]
__global__ void k_node_dots(const float* __restrict__ x, const float* __restrict__ w,
                            const float* __restrict__ bptr, float* __restrict__ xw1,
                            float* __restrict__ xw2, int N) {
  int wid = (blockIdx.x * blockDim.x + threadIdx.x) >> 6;
  int lane = threadIdx.x & 63;
  if (wid >= N) return;
  const float2* xr = (const float2*)(x + (size_t)wid * Cc);
  const float2* w2 = (const float2*)w;
  float2 v = xr[lane];
  float2 wa = w2[lane];
  float2 wb = w2[lane + 64];
  float s1 = v.x * wa.x + v.y * wa.y;
  float s2 = v.x * wb.x + v.y * wb.y;
#pragma unroll
  for (int off = 32; off >= 1; off >>= 1) {
    s1 += __shfl_xor(s1, off);
    s2 += __shfl_xor(s2, off);
  }
  if (lane == 0) {
    xw1[wid] = s1 + bptr[0];
    xw2[wid] = s2;
  }
}

// ---------------- edge scores + compaction. 1024-thread blocks: 1 hot-counter atomic per
// 1024 edges (782 total, ~9us serialized vs 34us at 256 — r12/r15 evidence). Iota folded.
__global__ void k_edge_score(const int* __restrict__ src, const int* __restrict__ dst,
                             const float* __restrict__ xw1, const float* __restrict__ xw2,
                             float* __restrict__ score, int2* __restrict__ cedge,
                             int* __restrict__ count, int* __restrict__ touched,
                             int* __restrict__ lab, int E, int N) {
  __shared__ int wcnt[16];
  __shared__ int blockbase;
  int e = blockIdx.x * blockDim.x + threadIdx.x;
  int wv = threadIdx.x >> 6, lane = threadIdx.x & 63;
  int s = 0, d = 0;
  bool con = false;
  if (e < E) {
    s = src[e];
    d = dst[e];
    float arg = xw1[s] + xw2[d];  // xw1 already includes bias
    score[e] = tanhf(arg);
    con = arg > 0.0f;  // tanh(arg) > 0 <=> arg > 0 (exact)
    if (con) {
      touched[s] = 1;  // racy same-value stores: benign
      touched[d] = 1;
    }
  }
  if (e < N) lab[e] = e;  // folded iota (E >= N)
  unsigned long long m = __ballot(con);
  int cnt = __popcll(m);
  if (lane == 0) wcnt[wv] = cnt;
  __syncthreads();
  if (threadIdx.x == 0) {
    int tot = 0;
    int pre[16];
#pragma unroll
    for (int j = 0; j < 16; ++j) {
      pre[j] = tot;
      tot += wcnt[j];
    }
    blockbase = tot ? atomicAdd(count, tot) : 0;
#pragma unroll
    for (int j = 0; j < 16; ++j) wcnt[j] = pre[j];
  }
  __syncthreads();
  if (con) {
    int pfx = __popcll(m & ((1ull << lane) - 1ull));
    cedge[blockbase + wcnt[wv] + pfx] = make_int2(s, d);
  }
}

// fused relax + double pointer-jump with change-flag early exit. Monotone atomicMin ->
// schedule-independent fixed point; a zero-change pass implies all later passes no-op.
__global__ void k_cc_pass(const int2* __restrict__ ce, const int* __restrict__ count,
                          int* __restrict__ lab, int* __restrict__ flags, int it, int N) {
  if (it > 0 && flags[it - 1] == 0) return;
  int i = blockIdx.x * blockDim.x + threadIdx.x;
  int M = *count;
  bool ch = false;
  if (i < M) {
    int2 p = ce[i];
    int a = lab[p.x], b = lab[p.y];
    if (a < b) {
      if (atomicMin(&lab[p.y], a) > a) ch = true;
    } else if (b < a) {
      if (atomicMin(&lab[p.x], b) > b) ch = true;
    }
  }
  if (i < N) {
    int a = lab[i];
    int b = lab[a];
    if (b < a) {
      atomicMin(&lab[i], b);
      ch = true;
    }
    a = lab[i];          // second jump (tree compression), monotone-safe
    b = lab[a];
    if (b < a) {
      atomicMin(&lab[i], b);
      ch = true;
    }
  }
  if (ch) flags[it] = 1;  // racy same-value store: benign
}

// ---------------- counting sort pass 1: per-chunk bucket histograms (LDS only)
__global__ void k_hist(const int* __restrict__ src, int* __restrict__ T, int E) {
  __shared__ int h[NB];
  for (int i = threadIdx.x; i < NB; i += blockDim.x) h[i] = 0;
  __syncthreads();
  int ch = (E + gridDim.x - 1) / gridDim.x;
  int lo = blockIdx.x * ch, hi = min(lo + ch, E);
  for (int e = lo + threadIdx.x; e < hi; e += blockDim.x) atomicAdd(&h[src[e] >> 6], 1);
  __syncthreads();
  for (int i = threadIdx.x; i < NB; i += blockDim.x) T[blockIdx.x * NB + i] = h[i];
}

// ---------------- pass 2: scan -> per-(chunk,bucket) global bases + bucket ranges bb[]
__global__ void k_scanT(int* __restrict__ T, int* __restrict__ bb, int C, int nb) {
  __shared__ int part[1024];
  int b = threadIdx.x;
  int tot = 0;
  for (int c = 0; c < C; ++c) tot += T[c * NB + b];
  part[b] = tot;
  __syncthreads();
  for (int d = 1; d < 1024; d <<= 1) {
    int v = (b >= d) ? part[b - d] : 0;
    __syncthreads();
    part[b] += v;
    __syncthreads();
  }
  int base = (b == 0) ? 0 : part[b - 1];  // exclusive prefix over buckets
  if (b <= nb) bb[b] = base;              // bb[nb] == E (buckets >= nb are empty)
  int run = base;
  for (int c = 0; c < C; ++c) {
    int v = T[c * NB + b];
    T[c * NB + b] = run;
    run += v;
  }
}

// ---------------- pass 3: scatter edge ids grouped by bucket (LDS cursors, deterministic)
__global__ void k_scat2(const int* __restrict__ src, const int* __restrict__ T,
                        int* __restrict__ pk, int E) {
  __shared__ int cur[NB];
  for (int i = threadIdx.x; i < NB; i += blockDim.x) cur[i] = T[blockIdx.x * NB + i];
  __syncthreads();
  int ch = (E + gridDim.x - 1) / gridDim.x;
  int lo = blockIdx.x * ch, hi = min(lo + ch, E);
  for (int e = lo + threadIdx.x; e < hi; e += blockDim.x) {
    int slot = atomicAdd(&cur[src[e] >> 6], 1);  // LDS atomic
    pk[slot] = e;
  }
}

// ---------------- pass 4: within-bucket sort by node -> pack(dst,score), cnt_src, csr_off
__global__ void k_bucket(const int* __restrict__ pk, const int* __restrict__ bb,
                         const int* __restrict__ src, const int* __restrict__ dst,
                         const float* __restrict__ score, int* __restrict__ cnt_src,
                         int* __restrict__ csr_off, int2* __restrict__ pack, int N) {
  int b = blockIdx.x;
  int lo = bb[b], hi = bb[b + 1];
  __shared__ int h[64], off_s[64], cur[64];
  if (threadIdx.x < 64) h[threadIdx.x] = 0;
  __syncthreads();
  for (int i = lo + threadIdx.x; i < hi; i += blockDim.x) atomicAdd(&h[src[pk[i]] & 63], 1);
  __syncthreads();
  if (threadIdx.x == 0) {
    int run = lo;
    for (int j = 0; j < 64; ++j) {
      off_s[j] = run;
      run += h[j];
    }
  }
  __syncthreads();
  if (threadIdx.x < 64) {
    cur[threadIdx.x] = off_s[threadIdx.x];
    int g = (b << 6) + threadIdx.x;
    if (g < N) {
      csr_off[g] = off_s[threadIdx.x];
      cnt_src[g] = h[threadIdx.x];
    }
  }
  __syncthreads();
  for (int i = lo + threadIdx.x; i < hi; i += blockDim.x) {
    int e = pk[i];
    int slot = atomicAdd(&cur[src[e] & 63], 1);  // LDS atomic
    pack[slot] = make_int2(dst[e], __float_as_int(score[e]));
  }
}

// gather: sx[u] = sum_edges score * x[dst] (+ x[u] if untouched). 2-edge unroll with
// int4 pack loads -> 2x memory-level parallelism on the pack->x dependent chain (r15:
// latency-bound at 2.34 TB/s, 89us).
__global__ void k_sx_csr(const int2* __restrict__ pack, const int* __restrict__ csr_off,
                         const int* __restrict__ cnt_src, const int* __restrict__ touched,
                         const float* __restrict__ x, float* __restrict__ sx, int N) {
  int wid = (blockIdx.x * blockDim.x + threadIdx.x) >> 6;
  int lane = threadIdx.x & 63;
  if (wid >= N) return;
  int beg = csr_off[wid], num = cnt_src[wid];
  float ax = 0.f, ay = 0.f;
  int k = 0;
  if ((beg & 1) && num > 0) {  // align to int4 boundary
    int2 p = pack[beg];
    float t = __int_as_float(p.y);
    float2 v = ((const float2*)(x + (size_t)p.x * Cc))[lane];
    ax += t * v.x;
    ay += t * v.y;
    k = 1;
  }
  for (; k + 1 < num; k += 2) {
    int4 pp = *((const int4*)(pack + beg + k));  // 16B-aligned: beg+k even
    float t0 = __int_as_float(pp.y);
    float t1 = __int_as_float(pp.w);
    float2 v0 = ((const float2*)(x + (size_t)pp.x * Cc))[lane];
    float2 v1 = ((const float2*)(x + (size_t)pp.z * Cc))[lane];
    ax += t0 * v0.x + t1 * v1.x;
    ay += t0 * v0.y + t1 * v1.y;
  }
  if (k < num) {
    int2 p = pack[beg + k];
    float t = __int_as_float(p.y);
    float2 v = ((const float2*)(x + (size_t)p.x * Cc))[lane];
    ax += t * v.x;
    ay += t * v.y;
  }
  if (touched[wid] == 0) {
    float2 v = ((const float2*)(x + (size_t)wid * Cc))[lane];
    ax += v.x;
    ay += v.y;
  }
  ((float2*)(sx + (size_t)wid * Cc))[lane] = make_float2(ax, ay);
}

// x_out[cluster] += sx, run-length compressed. One wave covers all 128 cols (float2);
// CHUNK=128 nodes/wave (r13 fix: hot-row flush atomics 16x fewer).
__global__ void k_segsum(const float* __restrict__ sx, const int* __restrict__ lab,
                         float* __restrict__ xout, int N) {
  const int CHUNK = 128;
  int wv = threadIdx.x >> 6;
  int lane = threadIdx.x & 63;
  int u0 = (blockIdx.x * 4 + wv) * CHUNK;
  if (u0 >= N) return;
  int u1 = min(u0 + CHUNK, N);
  int prevc = lab[u0];
  float ax = 0.f, ay = 0.f;
  for (int u = u0; u < u1; ++u) {
    int c = lab[u];
    float2 v = ((const float2*)(sx + (size_t)u * Cc))[lane];
    if (c != prevc) {
      float* row = xout + (size_t)prevc * Cc + 2 * lane;
      atomicAdd(row, ax);
      atomicAdd(row + 1, ay);
      ax = 0.f;
      ay = 0.f;
      prevc = c;
    }
    ax += v.x;
    ay += v.y;
  }
  float* row = xout + (size_t)prevc * Cc + 2 * lane;
  atomicAdd(row, ax);
  atomicAdd(row + 1, ay);
}

// merged edge + node outputs (saves a launch). Wave-aggregated batch atomicMax.
__global__ void k_outputs(const int* __restrict__ src, const int* __restrict__ dst,
                          const int* __restrict__ lab, const int* __restrict__ batch,
                          float* __restrict__ out_ei, float* __restrict__ out_cluster,
                          float* __restrict__ out_batch, int E, int N) {
  int i = blockIdx.x * blockDim.x + threadIdx.x;
  int lane = threadIdx.x & 63;
  if (i < E) {
    out_ei[i] = (float)lab[src[i]];
    out_ei[E + i] = (float)lab[dst[i]];
  }
  bool valid = i < N;
  int c = valid ? lab[i] : -1;
  float bv = valid ? (float)batch[i] : -1.f;
  if (valid) out_cluster[i] = (float)c;
  unsigned long long remaining = __ballot(valid);
  while (remaining) {
    int leader = __ffsll((unsigned long long)remaining) - 1;
    int lc = __shfl(c, leader);
    bool mine = valid && (c == lc);
    unsigned long long grp = __ballot(mine);
    float v = mine ? bv : -1.f;
#pragma unroll
    for (int off = 32; off >= 1; off >>= 1) v = fmaxf(v, __shfl_xor(v, off));
    if (lane == leader) atomicMax((int*)&out_batch[lc], __float_as_int(v));
    remaining &= ~grp;
  }
}

extern "C" void kernel_launch(void* const* d_in, const int* in_sizes, int n_in,
                              void* d_out, int out_size, void* d_ws, size_t ws_size,
                              hipStream_t stream) {
  const float* x = (const float*)d_in[0];
  const int* ei = (const int*)d_in[1];
  const int* batch = (const int*)d_in[2];
  const float* w = (const float*)d_in[3];
  const float* b = (const float*)d_in[4];
  const int N = in_sizes[2];
  const int E = in_sizes[1] / 2;
  const int* src = ei;
  const int* dst = ei + E;
  const int nb = (N + 63) >> 6;  // buckets; N=50000 -> 782 (<= NB)

  char* ws = (char*)d_ws;
  size_t off = 0;
  auto alloc = [&](size_t bytes) -> void* {
    void* p = ws + off;
    off = (off + bytes + 255) & ~(size_t)255;
    return p;
  };
  int* count = (int*)alloc(256);
  int* flags = (int*)alloc((size_t)MAXIT * 4);
  int* touched = (int*)alloc((size_t)N * 4);
  const size_t zero_bytes = off;  // count + flags + touched
  float* xw1 = (float*)alloc((size_t)N * 4);
  float* xw2 = (float*)alloc((size_t)N * 4);
  float* score = (float*)alloc((size_t)E * 4);
  int* lab = (int*)alloc((size_t)N * 4);
  int* cnt_src = (int*)alloc((size_t)N * 4);
  int* csr_off = (int*)alloc((size_t)N * 4);
  int* T = (int*)alloc((size_t)CH * NB * 4);
  int* bb = (int*)alloc((size_t)(NB + 1) * 4);
  int* pk = (int*)alloc((size_t)E * 4);
  int2* pack = (int2*)alloc((size_t)E * 8);
  float* sx = (float*)alloc((size_t)N * Cc * 4);
  int2* cedge = (int2*)sx;  // aliased: cedge dead before k_sx_csr writes sx
  (void)ws_size;            // ~41 MB total; r10 proved >= 43 MB available

  float* out_x = (float*)d_out;
  float* out_ei = out_x + (size_t)N * Cc;
  float* out_batch = out_ei + 2 * (size_t)E;
  float* out_cluster = out_batch + N;

  // zero only what is accumulated into: x_out (atomicAdd) and out_batch (atomicMax);
  // out_ei / out_cluster are fully overwritten by k_outputs
  hipMemsetAsync(out_x, 0, (size_t)N * Cc * 4, stream);
  hipMemsetAsync(out_batch, 0, (size_t)N * 4, stream);
  hipMemsetAsync(d_ws, 0, zero_bytes, stream);

  k_node_dots<<<(N + 3) / 4, 256, 0, stream>>>(x, w, b, xw1, xw2, N);
  k_edge_score<<<(E + 1023) / 1024, 1024, 0, stream>>>(src, dst, xw1, xw2, score, cedge,
                                                       count, touched, lab, E, N);
  for (int it = 0; it < MAXIT; ++it) {
    k_cc_pass<<<(E + 255) / 256, 256, 0, stream>>>(cedge, count, lab, flags, it, N);
  }
  // CSR build (no global atomics): hist -> scan -> bucket-scatter -> node-sort
  k_hist<<<CH, 256, 0, stream>>>(src, T, E);
  k_scanT<<<1, 1024, 0, stream>>>(T, bb, CH, nb);
  k_scat2<<<CH, 256, 0, stream>>>(src, T, pk, E);
  k_bucket<<<nb, 256, 0, stream>>>(pk, bb, src, dst, score, cnt_src, csr_off, pack, N);
  // cedge (aliased under sx) is dead from here on
  k_sx_csr<<<(N + 3) / 4, 256, 0, stream>>>(pack, csr_off, cnt_src, touched, x, sx, N);
  k_segsum<<<(N + 511) / 512, 256, 0, stream>>>(sx, lab, out_x, N);
  k_outputs<<<(E + 255) / 256, 256, 0, stream>>>(src, dst, lab, batch, out_ei, out_cluster,
                                                 out_batch, E, N);
}